// Round 1
// baseline (777.807 us; speedup 1.0000x reference)
//
#include <hip/hip_runtime.h>
#include <stdint.h>

#define NN 20000
#define NE 200000
// H=128, NH=8, HD=16, RBF=64

typedef __attribute__((ext_vector_type(8))) short bf16x8;
typedef __attribute__((ext_vector_type(4))) float f32x4;

__device__ __forceinline__ float bf2f(uint32_t u) {
  union { uint32_t i; float f; } v; v.i = u << 16; return v.f;
}
__device__ __forceinline__ uint16_t f2bf(float f) {
  union { float f; uint32_t i; } v; v.f = f;
  return (uint16_t)((v.i + 0x7fffu + ((v.i >> 16) & 1u)) >> 16);
}
__device__ __forceinline__ float siluf(float x) { return x / (1.f + __expf(-x)); }

// ---------------- prep kernels ----------------

// dst[c*K + k] = bf16(src[k*C + c])   (dst is [C rows][K cols])
__global__ void k_transpose_cast(const float* __restrict__ src, uint16_t* __restrict__ dst,
                                 int K, int C) {
  int idx = blockIdx.x * 256 + threadIdx.x;
  if (idx >= K * C) return;
  int c = idx / K, k = idx - c * K;
  dst[idx] = f2bf(src[(size_t)k * C + c]);
}

__global__ void k_bias_concat(const float* __restrict__ bq, const float* __restrict__ bk,
                              const float* __restrict__ bv, const float* __restrict__ bdk,
                              const float* __restrict__ bdv, float* __restrict__ Bqkv,
                              float* __restrict__ Bdkv) {
  int t = blockIdx.x * 256 + threadIdx.x;
  if (t < 640) Bqkv[t] = (t < 128) ? bq[t] : ((t < 256) ? bk[t - 128] : bv[t - 256]);
  if (t < 512) Bdkv[t] = (t < 128) ? bdk[t] : bdv[t - 128];
}

// LayerNorm over H=128 per node, one wave per node, output bf16
__global__ void k_ln_cast(const float* __restrict__ x, const float* __restrict__ s,
                          const float* __restrict__ b, uint16_t* __restrict__ out) {
  int gt = blockIdx.x * 256 + threadIdx.x;
  int node = gt >> 6, lane = gt & 63;
  if (node >= NN) return;
  const float* row = x + (size_t)node * 128;
  float2 v = *(const float2*)&row[lane * 2];
  float sum = v.x + v.y, sq = v.x * v.x + v.y * v.y;
  #pragma unroll
  for (int off = 32; off; off >>= 1) { sum += __shfl_xor(sum, off); sq += __shfl_xor(sq, off); }
  float mu = sum * (1.f / 128.f);
  float var = sq * (1.f / 128.f) - mu * mu;
  float rs = rsqrtf(var + 1e-6f);
  float o0 = (v.x - mu) * rs * s[lane * 2] + b[lane * 2];
  float o1 = (v.y - mu) * rs * s[lane * 2 + 1] + b[lane * 2 + 1];
  ((uint32_t*)out)[(size_t)node * 64 + lane] = (uint32_t)f2bf(o0) | ((uint32_t)f2bf(o1) << 16);
}

__global__ void k_cast_bf16(const float* __restrict__ src, uint16_t* __restrict__ dst, int npairs) {
  int i = blockIdx.x * 256 + threadIdx.x;
  if (i >= npairs) return;
  float2 v = ((const float2*)src)[i];
  ((uint32_t*)dst)[i] = (uint32_t)f2bf(v.x) | ((uint32_t)f2bf(v.y) << 16);
}

// ---------------- bf16 MFMA GEMM: C = act(A @ BT^T + bias) ----------------
// A [M,KTOT] bf16 row-major, BT [Fo,KTOT] bf16 row-major (i.e. W transposed).
// Tile 128x128, BK=64, 256 threads = 4 waves (2x2 of 64x64), 4x4 frags of 16x16x32.
// Fo must be a multiple of 128. M guarded.
template <int KTOT, bool OUT_BF16, bool SILU>
__global__ __launch_bounds__(256) void k_gemm(const uint16_t* __restrict__ A,
                                              const uint16_t* __restrict__ BT,
                                              const float* __restrict__ bias,
                                              void* __restrict__ Cout, int M, int Fo) {
  __shared__ __align__(16) uint16_t As[128 * 72];  // +8 bf16 pad: 144B stride, 2-way banks
  __shared__ __align__(16) uint16_t Bs[128 * 72];
  int t = threadIdx.x;
  int l = t & 63;
  int row0 = blockIdx.y * 128, col0 = blockIdx.x * 128;
  int wm = ((t >> 6) >> 1) * 64, wn = ((t >> 6) & 1) * 64;
  f32x4 acc[4][4] = {};
  for (int kt = 0; kt < KTOT; kt += 64) {
    __syncthreads();
    #pragma unroll
    for (int i = 0; i < 4; i++) {
      int c = i * 256 + t;          // 1024 x uint4 chunks per tile
      int row = c >> 3, ko = (c & 7) * 8;
      uint4 av = make_uint4(0u, 0u, 0u, 0u);
      int gr = row0 + row;
      if (gr < M) av = *(const uint4*)&A[(size_t)gr * KTOT + kt + ko];
      *(uint4*)&As[row * 72 + ko] = av;
      uint4 bw = *(const uint4*)&BT[(size_t)(col0 + row) * KTOT + kt + ko];
      *(uint4*)&Bs[row * 72 + ko] = bw;
    }
    __syncthreads();
    #pragma unroll
    for (int kk = 0; kk < 64; kk += 32) {
      bf16x8 af[4], bfr[4];
      #pragma unroll
      for (int mf = 0; mf < 4; mf++)
        af[mf] = *(const bf16x8*)&As[(wm + mf * 16 + (l & 15)) * 72 + (l >> 4) * 8 + kk];
      #pragma unroll
      for (int nf = 0; nf < 4; nf++)
        bfr[nf] = *(const bf16x8*)&Bs[(wn + nf * 16 + (l & 15)) * 72 + (l >> 4) * 8 + kk];
      #pragma unroll
      for (int mf = 0; mf < 4; mf++)
        #pragma unroll
        for (int nf = 0; nf < 4; nf++)
          acc[mf][nf] = __builtin_amdgcn_mfma_f32_16x16x32_bf16(af[mf], bfr[nf], acc[mf][nf], 0, 0, 0);
    }
  }
  float* Cf = (float*)Cout;
  uint16_t* Cb = (uint16_t*)Cout;
  #pragma unroll
  for (int mf = 0; mf < 4; mf++) {
    #pragma unroll
    for (int r = 0; r < 4; r++) {
      int grow = row0 + wm + mf * 16 + (l >> 4) * 4 + r;
      if (grow >= M) continue;
      #pragma unroll
      for (int nf = 0; nf < 4; nf++) {
        int gcol = col0 + wn + nf * 16 + (l & 15);
        float v = acc[mf][nf][r];
        if (bias) v += bias[gcol];
        if (SILU) v = siluf(v);
        if (OUT_BF16) Cb[(size_t)grow * Fo + gcol] = f2bf(v);
        else          Cf[(size_t)grow * Fo + gcol] = v;
      }
    }
  }
}

// ---------------- per-head LN on q/k (cols 0..255 of qkv_raw) -> bf16 ----------------
__global__ void k_headln(const float* __restrict__ qkv, const float* __restrict__ qs,
                         const float* __restrict__ qb, const float* __restrict__ ks,
                         const float* __restrict__ kb, uint16_t* __restrict__ out) {
  int idx = blockIdx.x * 256 + threadIdx.x;   // (n, part*8+h)
  if (idx >= NN * 16) return;
  int n = idx >> 4, ph = idx & 15, part = ph >> 3, h = ph & 7;
  const float* src = qkv + (size_t)n * 640 + part * 128 + h * 16;
  float v[16], sum = 0.f;
  #pragma unroll
  for (int i = 0; i < 16; i++) { v[i] = src[i]; sum += v[i]; }
  float mu = sum * (1.f / 16.f), var = 0.f;
  #pragma unroll
  for (int i = 0; i < 16; i++) { float d = v[i] - mu; var += d * d; }
  float rs = rsqrtf(var * (1.f / 16.f) + 1e-6f);
  const float* sc = part ? ks : qs;
  const float* bb = part ? kb : qb;
  uint16_t* dst = out + (size_t)n * 256 + part * 128 + h * 16;
  #pragma unroll
  for (int i = 0; i < 16; i++) dst[i] = f2bf((v[i] - mu) * rs * sc[i] + bb[i]);
}

// ---------------- edge attn ----------------
__device__ __forceinline__ float prod2(uint32_t q2, uint32_t k2, uint32_t d2) {
  return bf2f(q2 & 0xffffu) * bf2f(k2 & 0xffffu) * bf2f(d2 & 0xffffu)
       + bf2f(q2 >> 16) * bf2f(k2 >> 16) * bf2f(d2 >> 16);
}

__global__ void k_attn(const uint16_t* __restrict__ dkdv, const uint16_t* __restrict__ qk,
                       const int* __restrict__ snd, const int* __restrict__ rcv,
                       const float* __restrict__ ew, float* __restrict__ attn,
                       int e0, int ec) {
  int idx = blockIdx.x * 256 + threadIdx.x;   // (e_local, h)
  if (idx >= ec * 8) return;
  int el = idx >> 3, h = idx & 7;
  int e = e0 + el;
  int s = snd[e], r = rcv[e];
  const uint4* dk = (const uint4*)(dkdv + (size_t)el * 512 + h * 16);
  const uint4* qp = (const uint4*)(qk + (size_t)r * 256 + h * 16);
  const uint4* kp = (const uint4*)(qk + (size_t)s * 256 + 128 + h * 16);
  uint4 q0 = qp[0], q1 = qp[1], k0 = kp[0], k1 = kp[1], d0 = dk[0], d1 = dk[1];
  float dot = prod2(q0.x, k0.x, d0.x) + prod2(q0.y, k0.y, d0.y)
            + prod2(q0.z, k0.z, d0.z) + prod2(q0.w, k0.w, d0.w)
            + prod2(q1.x, k1.x, d1.x) + prod2(q1.y, k1.y, d1.y)
            + prod2(q1.z, k1.z, d1.z) + prod2(q1.w, k1.w, d1.w);
  float a = siluf(dot);
  float w = ew[e];
  float cut = (w < 5.f) ? 0.5f * (__cosf(w * 0.628318530717958648f) + 1.f) : 0.f;
  attn[(size_t)e * 8 + h] = a * cut;
}

// ---------------- edge message + scatter ----------------
__global__ void k_msg(const uint16_t* __restrict__ dkdv, const float* __restrict__ qkv,
                      const float* __restrict__ vec, const float* __restrict__ evec,
                      const float* __restrict__ attn, const int* __restrict__ snd,
                      const int* __restrict__ rcv, float* __restrict__ xagg,
                      float* __restrict__ vecagg, int e0, int ec) {
  int idx = blockIdx.x * 256 + threadIdx.x;   // (e_local, h*16+d)
  if (idx >= ec * 128) return;
  int el = idx >> 7, hd = idx & 127;
  int h = hd >> 4, d = hd & 15;
  int e = e0 + el;
  int s = snd[e], r = rcv[e];
  const uint16_t* dvp = dkdv + (size_t)el * 512 + 128 + h * 48 + d;
  float dv0 = bf2f(dvp[0]), dv1 = bf2f(dvp[16]), dv2 = bf2f(dvp[32]);
  const float* vsp = qkv + (size_t)s * 640 + 256 + h * 48 + d;  // v part of qkv_raw
  float a = attn[(size_t)e * 8 + h];
  float xm = vsp[0] * dv0 * a;
  float m1 = vsp[16] * dv1;
  float m2 = vsp[32] * dv2;
  atomicAdd(&xagg[(size_t)r * 128 + hd], xm);
  float e0v = evec[e * 3 + 0], e1v = evec[e * 3 + 1], e2v = evec[e * 3 + 2];
  const float* vv = vec + (size_t)s * 384;
  atomicAdd(&vecagg[((size_t)r * 3 + 0) * 128 + hd], vv[hd] * m1 + m2 * e0v);
  atomicAdd(&vecagg[((size_t)r * 3 + 1) * 128 + hd], vv[128 + hd] * m1 + m2 * e1v);
  atomicAdd(&vecagg[((size_t)r * 3 + 2) * 128 + hd], vv[256 + hd] * m1 + m2 * e2v);
}

// ---------------- final: dx = vec_dot*o2+o3 ; dvec = vec3*o1 + vec_agg ----------------
__global__ void k_final(const float* __restrict__ o, const uint16_t* __restrict__ vp,
                        float* __restrict__ dx, float* __restrict__ dvec) {
  int idx = blockIdx.x * 256 + threadIdx.x;
  if (idx >= NN * 128) return;
  int n = idx >> 7, j = idx & 127;
  const float* op = o + (size_t)n * 384;
  float o1 = op[j], o2 = op[128 + j], o3 = op[256 + j];
  const uint16_t* vpn = vp + (size_t)n * 3 * 384;
  float vd = 0.f;
  #pragma unroll
  for (int c = 0; c < 3; c++)
    vd += bf2f(vpn[c * 384 + j]) * bf2f(vpn[c * 384 + 128 + j]);
  dx[idx] = vd * o2 + o3;
  #pragma unroll
  for (int c = 0; c < 3; c++) {
    size_t vi = ((size_t)n * 3 + c) * 128 + j;
    dvec[vi] = bf2f(vpn[c * 384 + 256 + j]) * o1 + dvec[vi];
  }
}

static inline int cdiv_i(long long a, long long b) { return (int)((a + b - 1) / b); }

extern "C" void kernel_launch(void* const* d_in, const int* in_sizes, int n_in,
                              void* d_out, int out_size, void* d_ws, size_t ws_size,
                              hipStream_t stream) {
  const float* x    = (const float*)d_in[0];
  const float* vec  = (const float*)d_in[1];
  const float* ew   = (const float*)d_in[2];
  const float* ea   = (const float*)d_in[3];
  const float* evec = (const float*)d_in[4];
  const int*   snd  = (const int*)d_in[5];
  const int*   rcv  = (const int*)d_in[6];
  const float* ln_s = (const float*)d_in[7];
  const float* ln_b = (const float*)d_in[8];
  const float* Wq = (const float*)d_in[9];   const float* bq = (const float*)d_in[10];
  const float* Wk = (const float*)d_in[11];  const float* bk = (const float*)d_in[12];
  const float* Wv = (const float*)d_in[13];  const float* bv = (const float*)d_in[14];
  const float* Wvec = (const float*)d_in[15];
  const float* Wdk = (const float*)d_in[16]; const float* bdk = (const float*)d_in[17];
  const float* Wdv = (const float*)d_in[18]; const float* bdv = (const float*)d_in[19];
  const float* Wo = (const float*)d_in[20];  const float* bo = (const float*)d_in[21];
  const float* qln_s = (const float*)d_in[22]; const float* qln_b = (const float*)d_in[23];
  const float* kln_s = (const float*)d_in[24]; const float* kln_b = (const float*)d_in[25];
  (void)in_sizes; (void)n_in;

  // ---- workspace carve (fixed part ~196.5 MB) ----
  uint8_t* p = (uint8_t*)d_ws;
  auto alloc = [&](size_t bytes) -> uint8_t* {
    uint8_t* r = p; p += (bytes + 255) & ~(size_t)255; return r;
  };
  uint16_t* WTqkv = (uint16_t*)alloc(640 * 128 * 2);
  float*    Bqkv  = (float*)alloc(640 * 4);
  uint16_t* WTvec = (uint16_t*)alloc(384 * 128 * 2);
  uint16_t* WTdkv = (uint16_t*)alloc(512 * 64 * 2);
  float*    Bdkv  = (float*)alloc(512 * 4);
  uint16_t* WTo   = (uint16_t*)alloc(384 * 128 * 2);
  uint16_t* xn_b  = (uint16_t*)alloc((size_t)NN * 128 * 2);
  float*    qkv   = (float*)alloc((size_t)NN * 640 * 4);
  uint16_t* qk_b  = (uint16_t*)alloc((size_t)NN * 256 * 2);
  uint16_t* vec_b = (uint16_t*)alloc((size_t)NN * 3 * 128 * 2);
  uint16_t* vp    = (uint16_t*)alloc((size_t)NN * 3 * 384 * 2);   // bf16 vp
  uint16_t* ea_b  = (uint16_t*)alloc((size_t)NE * 64 * 2);
  float*    attn  = (float*)alloc((size_t)NE * 8 * 4);
  uint16_t* xagg_b = (uint16_t*)alloc((size_t)NN * 128 * 2);
  float*    o     = (float*)alloc((size_t)NN * 384 * 4);
  size_t used = (size_t)(p - (uint8_t*)d_ws);
  size_t rem = ws_size > used ? ws_size - used : 0;
  long long chl = (long long)(rem / 1024);  // 512 bf16 per edge
  int CH = (chl >= NE) ? NE : (int)chl;
  if (CH < 128) CH = 128;
  uint16_t* dkdv = (uint16_t*)alloc((size_t)CH * 512 * 2);

  float* xagg = (float*)d_out;                         // [NN,128] -> later dx
  float* vecagg = (float*)d_out + (size_t)NN * 128;    // [NN,3,128] -> later dvec

  hipMemsetAsync(d_out, 0, (size_t)out_size * 4, stream);

  // weights prep
  k_transpose_cast<<<cdiv_i(128 * 128, 256), 256, 0, stream>>>(Wq, WTqkv, 128, 128);
  k_transpose_cast<<<cdiv_i(128 * 128, 256), 256, 0, stream>>>(Wk, WTqkv + 128 * 128, 128, 128);
  k_transpose_cast<<<cdiv_i(384 * 128, 256), 256, 0, stream>>>(Wv, WTqkv + 256 * 128, 128, 384);
  k_transpose_cast<<<cdiv_i(384 * 128, 256), 256, 0, stream>>>(Wvec, WTvec, 128, 384);
  k_transpose_cast<<<cdiv_i(128 * 64, 256), 256, 0, stream>>>(Wdk, WTdkv, 64, 128);
  k_transpose_cast<<<cdiv_i(384 * 64, 256), 256, 0, stream>>>(Wdv, WTdkv + 128 * 64, 64, 384);
  k_transpose_cast<<<cdiv_i(384 * 128, 256), 256, 0, stream>>>(Wo, WTo, 128, 384);
  k_bias_concat<<<3, 256, 0, stream>>>(bq, bk, bv, bdk, bdv, Bqkv, Bdkv);

  // node pre
  k_ln_cast<<<cdiv_i((long long)NN * 64, 256), 256, 0, stream>>>(x, ln_s, ln_b, xn_b);
  k_cast_bf16<<<cdiv_i((long long)NN * 3 * 64, 256), 256, 0, stream>>>(vec, vec_b, NN * 3 * 64);
  k_cast_bf16<<<cdiv_i((long long)NE * 32, 256), 256, 0, stream>>>(ea, ea_b, NE * 32);

  // qkv = xn @ [Wq|Wk|Wv] + b
  { dim3 g(640 / 128, cdiv_i(NN, 128));
    k_gemm<128, false, false><<<g, 256, 0, stream>>>(xn_b, WTqkv, Bqkv, qkv, NN, 640); }
  k_headln<<<cdiv_i((long long)NN * 16, 256), 256, 0, stream>>>(qkv, qln_s, qln_b, kln_s, kln_b, qk_b);

  // vp = vec @ Wvec (bf16 out)
  { dim3 g(384 / 128, cdiv_i((long long)NN * 3, 128));
    k_gemm<128, true, false><<<g, 256, 0, stream>>>(vec_b, WTvec, nullptr, vp, NN * 3, 384); }

  // edges, chunked by workspace budget
  for (int e0 = 0; e0 < NE; e0 += CH) {
    int ec = (NE - e0 < CH) ? (NE - e0) : CH;
    dim3 g(512 / 128, cdiv_i(ec, 128));
    k_gemm<64, true, true><<<g, 256, 0, stream>>>(ea_b + (size_t)e0 * 64, WTdkv, Bdkv, dkdv, ec, 512);
    k_attn<<<cdiv_i((long long)ec * 8, 256), 256, 0, stream>>>(dkdv, qk_b, snd, rcv, ew, attn, e0, ec);
    k_msg<<<cdiv_i((long long)ec * 128, 256), 256, 0, stream>>>(dkdv, qkv, vec, evec, attn, snd, rcv,
                                                                xagg, vecagg, e0, ec);
  }

  // o = x_agg @ Wo + bo
  k_cast_bf16<<<cdiv_i((long long)NN * 64, 256), 256, 0, stream>>>(xagg, xagg_b, NN * 64);
  { dim3 g(384 / 128, cdiv_i(NN, 128));
    k_gemm<128, false, false><<<g, 256, 0, stream>>>(xagg_b, WTo, bo, o, NN, 384); }

  // outputs
  k_final<<<cdiv_i((long long)NN * 128, 256), 256, 0, stream>>>(o, vp, xagg, vecagg);
}

// Round 2
// 496.830 us; speedup vs baseline: 1.5655x; 1.5655x over previous
//
#include <hip/hip_runtime.h>
#include <stdint.h>

#define NN 20000
#define NE 200000
// H=128, NH=8, HD=16, RBF=64

typedef __attribute__((ext_vector_type(8))) short bf16x8;
typedef __attribute__((ext_vector_type(4))) float f32x4;

__device__ __forceinline__ float bf2f(uint32_t u) {
  union { uint32_t i; float f; } v; v.i = u << 16; return v.f;
}
__device__ __forceinline__ uint16_t f2bf(float f) {
  union { float f; uint32_t i; } v; v.f = f;
  return (uint16_t)((v.i + 0x7fffu + ((v.i >> 16) & 1u)) >> 16);
}
__device__ __forceinline__ float siluf(float x) { return x / (1.f + __expf(-x)); }

// ---------------- prep kernels ----------------

// dst[c*K + k] = bf16(src[k*C + c])   (dst is [C rows][K cols])
__global__ void k_transpose_cast(const float* __restrict__ src, uint16_t* __restrict__ dst,
                                 int K, int C) {
  int idx = blockIdx.x * 256 + threadIdx.x;
  if (idx >= K * C) return;
  int c = idx / K, k = idx - c * K;
  dst[idx] = f2bf(src[(size_t)k * C + c]);
}

__global__ void k_bias_concat(const float* __restrict__ bq, const float* __restrict__ bk,
                              const float* __restrict__ bv, const float* __restrict__ bdk,
                              const float* __restrict__ bdv, float* __restrict__ Bqkv,
                              float* __restrict__ Bdkv) {
  int t = blockIdx.x * 256 + threadIdx.x;
  if (t < 640) Bqkv[t] = (t < 128) ? bq[t] : ((t < 256) ? bk[t - 128] : bv[t - 256]);
  if (t < 512) Bdkv[t] = (t < 128) ? bdk[t] : bdv[t - 128];
}

// LayerNorm over H=128 per node, one wave per node, output bf16
__global__ void k_ln_cast(const float* __restrict__ x, const float* __restrict__ s,
                          const float* __restrict__ b, uint16_t* __restrict__ out) {
  int gt = blockIdx.x * 256 + threadIdx.x;
  int node = gt >> 6, lane = gt & 63;
  if (node >= NN) return;
  const float* row = x + (size_t)node * 128;
  float2 v = *(const float2*)&row[lane * 2];
  float sum = v.x + v.y, sq = v.x * v.x + v.y * v.y;
  #pragma unroll
  for (int off = 32; off; off >>= 1) { sum += __shfl_xor(sum, off); sq += __shfl_xor(sq, off); }
  float mu = sum * (1.f / 128.f);
  float var = sq * (1.f / 128.f) - mu * mu;
  float rs = rsqrtf(var + 1e-6f);
  float o0 = (v.x - mu) * rs * s[lane * 2] + b[lane * 2];
  float o1 = (v.y - mu) * rs * s[lane * 2 + 1] + b[lane * 2 + 1];
  ((uint32_t*)out)[(size_t)node * 64 + lane] = (uint32_t)f2bf(o0) | ((uint32_t)f2bf(o1) << 16);
}

__global__ void k_cast_bf16(const float* __restrict__ src, uint16_t* __restrict__ dst, int npairs) {
  int i = blockIdx.x * 256 + threadIdx.x;
  if (i >= npairs) return;
  float2 v = ((const float2*)src)[i];
  ((uint32_t*)dst)[i] = (uint32_t)f2bf(v.x) | ((uint32_t)f2bf(v.y) << 16);
}

// cast v-part of qkv (cols 256..639) to bf16 [N,384]
__global__ void k_vcast(const float* __restrict__ qkv, uint16_t* __restrict__ v_b) {
  int idx = blockIdx.x * 256 + threadIdx.x;
  if (idx >= NN * 192) return;
  int n = idx / 192, r = idx - n * 192;
  float2 v = *(const float2*)&qkv[(size_t)n * 640 + 256 + r * 2];
  ((uint32_t*)v_b)[(size_t)n * 192 + r] = (uint32_t)f2bf(v.x) | ((uint32_t)f2bf(v.y) << 16);
}

// ---------------- edge sort by receiver (counting sort) ----------------
__global__ void k_hist(const int* __restrict__ rcv, int* __restrict__ deg) {
  int e = blockIdx.x * 256 + threadIdx.x;
  if (e < NE) atomicAdd(&deg[rcv[e]], 1);
}

__global__ void k_scan(const int* __restrict__ deg, int* __restrict__ off, int* __restrict__ cur) {
  __shared__ int wsum[4];
  __shared__ int carry;
  int t = threadIdx.x, lane = t & 63, w = t >> 6;
  if (t == 0) carry = 0;
  __syncthreads();
  for (int base = 0; base < NN; base += 256) {
    int i = base + t;
    int x = (i < NN) ? deg[i] : 0;
    int v = x;
    #pragma unroll
    for (int d = 1; d < 64; d <<= 1) {
      int y = __shfl_up(v, d);
      if (lane >= d) v += y;
    }
    if (lane == 63) wsum[w] = v;
    __syncthreads();
    int wadd = 0;
    for (int j = 0; j < w; j++) wadd += wsum[j];
    int excl = carry + wadd + v - x;
    if (i < NN) { off[i] = excl; cur[i] = excl; }
    __syncthreads();
    if (t == 255) carry += wsum[0] + wsum[1] + wsum[2] + wsum[3];
    __syncthreads();
  }
  if (t == 0) off[NN] = carry;
}

__global__ void k_scatter(const int* __restrict__ rcv, int* __restrict__ cur,
                          int* __restrict__ perm) {
  int e = blockIdx.x * 256 + threadIdx.x;
  if (e >= NE) return;
  int pos = atomicAdd(&cur[rcv[e]], 1);
  perm[pos] = e;
}

// gather+cast edge_attr rows in permuted order: ea_perm[i] = bf16(ea[perm[i]])
__global__ void k_permute_ea(const float* __restrict__ ea, const int* __restrict__ perm,
                             uint16_t* __restrict__ ea_perm) {
  int idx = blockIdx.x * 256 + threadIdx.x;   // one float4 per thread
  if (idx >= NE * 16) return;
  int i = idx >> 4, j = (idx & 15) * 4;
  float4 v = *(const float4*)&ea[(size_t)perm[i] * 64 + j];
  uint2 o;
  o.x = (uint32_t)f2bf(v.x) | ((uint32_t)f2bf(v.y) << 16);
  o.y = (uint32_t)f2bf(v.z) | ((uint32_t)f2bf(v.w) << 16);
  *(uint2*)&ea_perm[(size_t)i * 64 + j] = o;
}

// ---------------- bf16 MFMA GEMM: C = act(A @ BT^T + bias) ----------------
template <int KTOT, bool OUT_BF16, bool SILU>
__global__ __launch_bounds__(256) void k_gemm(const uint16_t* __restrict__ A,
                                              const uint16_t* __restrict__ BT,
                                              const float* __restrict__ bias,
                                              void* __restrict__ Cout, int M, int Fo) {
  __shared__ __align__(16) uint16_t As[128 * 72];
  __shared__ __align__(16) uint16_t Bs[128 * 72];
  int t = threadIdx.x;
  int l = t & 63;
  int row0 = blockIdx.y * 128, col0 = blockIdx.x * 128;
  int wm = ((t >> 6) >> 1) * 64, wn = ((t >> 6) & 1) * 64;
  f32x4 acc[4][4] = {};
  for (int kt = 0; kt < KTOT; kt += 64) {
    __syncthreads();
    #pragma unroll
    for (int i = 0; i < 4; i++) {
      int c = i * 256 + t;
      int row = c >> 3, ko = (c & 7) * 8;
      uint4 av = make_uint4(0u, 0u, 0u, 0u);
      int gr = row0 + row;
      if (gr < M) av = *(const uint4*)&A[(size_t)gr * KTOT + kt + ko];
      *(uint4*)&As[row * 72 + ko] = av;
      uint4 bw = *(const uint4*)&BT[(size_t)(col0 + row) * KTOT + kt + ko];
      *(uint4*)&Bs[row * 72 + ko] = bw;
    }
    __syncthreads();
    #pragma unroll
    for (int kk = 0; kk < 64; kk += 32) {
      bf16x8 af[4], bfr[4];
      #pragma unroll
      for (int mf = 0; mf < 4; mf++)
        af[mf] = *(const bf16x8*)&As[(wm + mf * 16 + (l & 15)) * 72 + (l >> 4) * 8 + kk];
      #pragma unroll
      for (int nf = 0; nf < 4; nf++)
        bfr[nf] = *(const bf16x8*)&Bs[(wn + nf * 16 + (l & 15)) * 72 + (l >> 4) * 8 + kk];
      #pragma unroll
      for (int mf = 0; mf < 4; mf++)
        #pragma unroll
        for (int nf = 0; nf < 4; nf++)
          acc[mf][nf] = __builtin_amdgcn_mfma_f32_16x16x32_bf16(af[mf], bfr[nf], acc[mf][nf], 0, 0, 0);
    }
  }
  float* Cf = (float*)Cout;
  uint16_t* Cb = (uint16_t*)Cout;
  #pragma unroll
  for (int mf = 0; mf < 4; mf++) {
    #pragma unroll
    for (int r = 0; r < 4; r++) {
      int grow = row0 + wm + mf * 16 + (l >> 4) * 4 + r;
      if (grow >= M) continue;
      #pragma unroll
      for (int nf = 0; nf < 4; nf++) {
        int gcol = col0 + wn + nf * 16 + (l & 15);
        float v = acc[mf][nf][r];
        if (bias) v += bias[gcol];
        if (SILU) v = siluf(v);
        if (OUT_BF16) Cb[(size_t)grow * Fo + gcol] = f2bf(v);
        else          Cf[(size_t)grow * Fo + gcol] = v;
      }
    }
  }
}

// dkdv GEMM over a node-chunk's edge range [off[n0], off[n1]) read from device.
// A row i (local) = ea_perm[e0+i]; C row i = dkdv[i]. KTOT=64, Fo=512, silu, bf16 out.
__global__ __launch_bounds__(256) void k_gemm_dkv(const uint16_t* __restrict__ Aperm,
                                                  const int* __restrict__ pbeg,
                                                  const int* __restrict__ pend,
                                                  const uint16_t* __restrict__ BT,
                                                  const float* __restrict__ bias,
                                                  uint16_t* __restrict__ Cout, int Mcap) {
  int e0 = pbeg[0];
  int M = pend[0] - e0;
  if (M > Mcap) M = Mcap;
  int row0 = blockIdx.y * 128, col0 = blockIdx.x * 128;
  if (row0 >= M) return;
  const uint16_t* A = Aperm + (size_t)e0 * 64;
  __shared__ __align__(16) uint16_t As[128 * 72];
  __shared__ __align__(16) uint16_t Bs[128 * 72];
  int t = threadIdx.x;
  int l = t & 63;
  int wm = ((t >> 6) >> 1) * 64, wn = ((t >> 6) & 1) * 64;
  f32x4 acc[4][4] = {};
  {
    #pragma unroll
    for (int i = 0; i < 4; i++) {
      int c = i * 256 + t;
      int row = c >> 3, ko = (c & 7) * 8;
      uint4 av = make_uint4(0u, 0u, 0u, 0u);
      if (row0 + row < M) av = *(const uint4*)&A[(size_t)(row0 + row) * 64 + ko];
      *(uint4*)&As[row * 72 + ko] = av;
      uint4 bw = *(const uint4*)&BT[(size_t)(col0 + row) * 64 + ko];
      *(uint4*)&Bs[row * 72 + ko] = bw;
    }
    __syncthreads();
    #pragma unroll
    for (int kk = 0; kk < 64; kk += 32) {
      bf16x8 af[4], bfr[4];
      #pragma unroll
      for (int mf = 0; mf < 4; mf++)
        af[mf] = *(const bf16x8*)&As[(wm + mf * 16 + (l & 15)) * 72 + (l >> 4) * 8 + kk];
      #pragma unroll
      for (int nf = 0; nf < 4; nf++)
        bfr[nf] = *(const bf16x8*)&Bs[(wn + nf * 16 + (l & 15)) * 72 + (l >> 4) * 8 + kk];
      #pragma unroll
      for (int mf = 0; mf < 4; mf++)
        #pragma unroll
        for (int nf = 0; nf < 4; nf++)
          acc[mf][nf] = __builtin_amdgcn_mfma_f32_16x16x32_bf16(af[mf], bfr[nf], acc[mf][nf], 0, 0, 0);
    }
  }
  #pragma unroll
  for (int mf = 0; mf < 4; mf++) {
    #pragma unroll
    for (int r = 0; r < 4; r++) {
      int grow = row0 + wm + mf * 16 + (l >> 4) * 4 + r;
      if (grow >= M) continue;
      #pragma unroll
      for (int nf = 0; nf < 4; nf++) {
        int gcol = col0 + wn + nf * 16 + (l & 15);
        float v = siluf(acc[mf][nf][r] + bias[gcol]);
        Cout[(size_t)grow * 512 + gcol] = f2bf(v);
      }
    }
  }
}

// ---------------- per-head LN on q/k -> bf16 ----------------
__global__ void k_headln(const float* __restrict__ qkv, const float* __restrict__ qs,
                         const float* __restrict__ qb, const float* __restrict__ ks,
                         const float* __restrict__ kb, uint16_t* __restrict__ out) {
  int idx = blockIdx.x * 256 + threadIdx.x;
  if (idx >= NN * 16) return;
  int n = idx >> 4, ph = idx & 15, part = ph >> 3, h = ph & 7;
  const float* src = qkv + (size_t)n * 640 + part * 128 + h * 16;
  float v[16], sum = 0.f;
  #pragma unroll
  for (int i = 0; i < 16; i++) { v[i] = src[i]; sum += v[i]; }
  float mu = sum * (1.f / 16.f), var = 0.f;
  #pragma unroll
  for (int i = 0; i < 16; i++) { float d = v[i] - mu; var += d * d; }
  float rs = rsqrtf(var * (1.f / 16.f) + 1e-6f);
  const float* sc = part ? ks : qs;
  const float* bb = part ? kb : qb;
  uint16_t* dst = out + (size_t)n * 256 + part * 128 + h * 16;
  #pragma unroll
  for (int i = 0; i < 16; i++) dst[i] = f2bf((v[i] - mu) * rs * sc[i] + bb[i]);
}

// ---------------- fused attn + message + segment aggregation ----------------
// One 128-thread block per receiver node; edges sorted by receiver; no atomics.
__global__ __launch_bounds__(128) void k_agg(
    const uint16_t* __restrict__ dkdv, const int* __restrict__ off,
    const int* __restrict__ perm, const int* __restrict__ snd,
    const float* __restrict__ ew, const float* __restrict__ evec,
    const uint16_t* __restrict__ qk_b, const uint16_t* __restrict__ v_b,
    const uint16_t* __restrict__ vec_b, float* __restrict__ xagg,
    float* __restrict__ vecagg, int n0, int n1, int Mcap) {
  int n = n0 + blockIdx.x;
  if (n >= n1) return;
  int hd = threadIdx.x, h = hd >> 4, d = hd & 15;
  int i0 = off[n], i1 = off[n + 1];
  int ebase = off[n0];
  float q = bf2f(qk_b[(size_t)n * 256 + hd]);
  int vb = h * 48 + d;
  float ax = 0.f, a0 = 0.f, a1 = 0.f, a2 = 0.f;
  for (int i = i0; i < i1; i++) {
    int li = i - ebase;
    if (li >= Mcap) break;
    int e = perm[i];
    int s = snd[e];
    const uint16_t* row = dkdv + (size_t)li * 512;
    float dk = bf2f(row[hd]);
    float kv = bf2f(qk_b[(size_t)s * 256 + 128 + hd]);
    float t = q * kv * dk;
    t += __shfl_xor(t, 1); t += __shfl_xor(t, 2);
    t += __shfl_xor(t, 4); t += __shfl_xor(t, 8);
    float w = ew[e];
    float cut = (w < 5.f) ? 0.5f * (__cosf(w * 0.628318530717958648f) + 1.f) : 0.f;
    float a = (t / (1.f + __expf(-t))) * cut;
    float dv0 = bf2f(row[128 + vb]), dv1 = bf2f(row[144 + vb]), dv2 = bf2f(row[160 + vb]);
    const uint16_t* vsp = v_b + (size_t)s * 384 + vb;
    float m1 = bf2f(vsp[16]) * dv1;
    float m2 = bf2f(vsp[32]) * dv2;
    ax += bf2f(vsp[0]) * dv0 * a;
    const uint16_t* vv = vec_b + (size_t)s * 384;
    a0 += bf2f(vv[hd]) * m1 + m2 * evec[e * 3];
    a1 += bf2f(vv[128 + hd]) * m1 + m2 * evec[e * 3 + 1];
    a2 += bf2f(vv[256 + hd]) * m1 + m2 * evec[e * 3 + 2];
  }
  xagg[(size_t)n * 128 + hd] = ax;
  vecagg[((size_t)n * 3 + 0) * 128 + hd] = a0;
  vecagg[((size_t)n * 3 + 1) * 128 + hd] = a1;
  vecagg[((size_t)n * 3 + 2) * 128 + hd] = a2;
}

// ---------------- final: dx = vec_dot*o2+o3 ; dvec = vec3*o1 + vec_agg ----------------
__global__ void k_final(const float* __restrict__ o, const uint16_t* __restrict__ vp,
                        float* __restrict__ dx, float* __restrict__ dvec) {
  int idx = blockIdx.x * 256 + threadIdx.x;
  if (idx >= NN * 128) return;
  int n = idx >> 7, j = idx & 127;
  const float* op = o + (size_t)n * 384;
  float o1 = op[j], o2 = op[128 + j], o3 = op[256 + j];
  const uint16_t* vpn = vp + (size_t)n * 3 * 384;
  float vd = 0.f;
  #pragma unroll
  for (int c = 0; c < 3; c++)
    vd += bf2f(vpn[c * 384 + j]) * bf2f(vpn[c * 384 + 128 + j]);
  dx[idx] = vd * o2 + o3;
  #pragma unroll
  for (int c = 0; c < 3; c++) {
    size_t vi = ((size_t)n * 3 + c) * 128 + j;
    dvec[vi] = bf2f(vpn[c * 384 + 256 + j]) * o1 + dvec[vi];
  }
}

static inline int cdiv_i(long long a, long long b) { return (int)((a + b - 1) / b); }

extern "C" void kernel_launch(void* const* d_in, const int* in_sizes, int n_in,
                              void* d_out, int out_size, void* d_ws, size_t ws_size,
                              hipStream_t stream) {
  const float* x    = (const float*)d_in[0];
  const float* vec  = (const float*)d_in[1];
  const float* ew   = (const float*)d_in[2];
  const float* ea   = (const float*)d_in[3];
  const float* evec = (const float*)d_in[4];
  const int*   snd  = (const int*)d_in[5];
  const int*   rcv  = (const int*)d_in[6];
  const float* ln_s = (const float*)d_in[7];
  const float* ln_b = (const float*)d_in[8];
  const float* Wq = (const float*)d_in[9];   const float* bq = (const float*)d_in[10];
  const float* Wk = (const float*)d_in[11];  const float* bk = (const float*)d_in[12];
  const float* Wv = (const float*)d_in[13];  const float* bv = (const float*)d_in[14];
  const float* Wvec = (const float*)d_in[15];
  const float* Wdk = (const float*)d_in[16]; const float* bdk = (const float*)d_in[17];
  const float* Wdv = (const float*)d_in[18]; const float* bdv = (const float*)d_in[19];
  const float* Wo = (const float*)d_in[20];  const float* bo = (const float*)d_in[21];
  const float* qln_s = (const float*)d_in[22]; const float* qln_b = (const float*)d_in[23];
  const float* kln_s = (const float*)d_in[24]; const float* kln_b = (const float*)d_in[25];
  (void)in_sizes; (void)n_in; (void)out_size;

  uint8_t* p = (uint8_t*)d_ws;
  auto alloc = [&](size_t bytes) -> uint8_t* {
    uint8_t* r = p; p += (bytes + 255) & ~(size_t)255; return r;
  };
  uint16_t* WTqkv = (uint16_t*)alloc(640 * 128 * 2);
  float*    Bqkv  = (float*)alloc(640 * 4);
  uint16_t* WTvec = (uint16_t*)alloc(384 * 128 * 2);
  uint16_t* WTdkv = (uint16_t*)alloc(512 * 64 * 2);
  float*    Bdkv  = (float*)alloc(512 * 4);
  uint16_t* WTo   = (uint16_t*)alloc(384 * 128 * 2);
  int*      deg   = (int*)alloc(NN * 4);
  int*      off   = (int*)alloc((NN + 1) * 4);
  int*      cur   = (int*)alloc(NN * 4);
  int*      perm  = (int*)alloc((size_t)NE * 4);
  uint16_t* xn_b  = (uint16_t*)alloc((size_t)NN * 128 * 2);
  float*    qkv   = (float*)alloc((size_t)NN * 640 * 4);   // reused later for o + xagg_b
  uint16_t* qk_b  = (uint16_t*)alloc((size_t)NN * 256 * 2);
  uint16_t* v_b   = (uint16_t*)alloc((size_t)NN * 384 * 2);
  uint16_t* vec_b = (uint16_t*)alloc((size_t)NN * 3 * 128 * 2);
  uint16_t* vp    = (uint16_t*)alloc((size_t)NN * 3 * 384 * 2);
  uint16_t* ea_perm = (uint16_t*)alloc((size_t)NE * 64 * 2);
  size_t fixed = (size_t)(p - (uint8_t*)d_ws);

  // adaptive node-chunking for the dkdv buffer
  int nchunk = 1;
  long long CHmax = NE;
  for (nchunk = 1; nchunk <= 64; nchunk++) {
    long long base = (NE + nchunk - 1) / nchunk;
    CHmax = (nchunk == 1) ? (long long)NE : base + base / 4;   // 1.25x margin
    if (fixed + (size_t)CHmax * 1024 + 4096 <= ws_size) break;
  }
  uint16_t* dkdv = (uint16_t*)alloc((size_t)CHmax * 1024);
  int NB = cdiv_i(NN, nchunk);

  // dead-qkv reuse for epilogue buffers
  float*    o      = qkv;                                   // [NN,384] f32 = 30.7MB
  uint16_t* xagg_b = (uint16_t*)(qkv + (size_t)NN * 384);   // [NN,128] bf16 = 5.1MB

  float* xagg   = (float*)d_out;
  float* vecagg = (float*)d_out + (size_t)NN * 128;

  // ---- weights prep ----
  k_transpose_cast<<<cdiv_i(128 * 128, 256), 256, 0, stream>>>(Wq, WTqkv, 128, 128);
  k_transpose_cast<<<cdiv_i(128 * 128, 256), 256, 0, stream>>>(Wk, WTqkv + 128 * 128, 128, 128);
  k_transpose_cast<<<cdiv_i(384 * 128, 256), 256, 0, stream>>>(Wv, WTqkv + 256 * 128, 128, 384);
  k_transpose_cast<<<cdiv_i(384 * 128, 256), 256, 0, stream>>>(Wvec, WTvec, 128, 384);
  k_transpose_cast<<<cdiv_i(128 * 64, 256), 256, 0, stream>>>(Wdk, WTdkv, 64, 128);
  k_transpose_cast<<<cdiv_i(384 * 64, 256), 256, 0, stream>>>(Wdv, WTdkv + 128 * 64, 64, 384);
  k_transpose_cast<<<cdiv_i(384 * 128, 256), 256, 0, stream>>>(Wo, WTo, 128, 384);
  k_bias_concat<<<3, 256, 0, stream>>>(bq, bk, bv, bdk, bdv, Bqkv, Bdkv);

  // ---- edge sort by receiver ----
  hipMemsetAsync(deg, 0, NN * 4, stream);
  k_hist<<<cdiv_i(NE, 256), 256, 0, stream>>>(rcv, deg);
  k_scan<<<1, 256, 0, stream>>>(deg, off, cur);
  k_scatter<<<cdiv_i(NE, 256), 256, 0, stream>>>(rcv, cur, perm);
  k_permute_ea<<<cdiv_i((long long)NE * 16, 256), 256, 0, stream>>>(ea, perm, ea_perm);

  // ---- node pre ----
  k_ln_cast<<<cdiv_i((long long)NN * 64, 256), 256, 0, stream>>>(x, ln_s, ln_b, xn_b);
  k_cast_bf16<<<cdiv_i((long long)NN * 3 * 64, 256), 256, 0, stream>>>(vec, vec_b, NN * 3 * 64);

  // qkv = xn @ [Wq|Wk|Wv] + b
  { dim3 g(640 / 128, cdiv_i(NN, 128));
    k_gemm<128, false, false><<<g, 256, 0, stream>>>(xn_b, WTqkv, Bqkv, qkv, NN, 640); }
  k_headln<<<cdiv_i((long long)NN * 16, 256), 256, 0, stream>>>(qkv, qln_s, qln_b, kln_s, kln_b, qk_b);
  k_vcast<<<cdiv_i((long long)NN * 192, 256), 256, 0, stream>>>(qkv, v_b);

  // vp = vec @ Wvec (bf16 out)
  { dim3 g(384 / 128, cdiv_i((long long)NN * 3, 128));
    k_gemm<128, true, false><<<g, 256, 0, stream>>>(vec_b, WTvec, nullptr, vp, NN * 3, 384); }

  // ---- edge phase: per node-chunk, dkdv GEMM then segment aggregation ----
  for (int c = 0; c < nchunk; c++) {
    int nlo = c * NB, nhi = (c + 1) * NB; if (nhi > NN) nhi = NN;
    if (nlo >= nhi) break;
    dim3 g(512 / 128, cdiv_i(CHmax, 128));
    k_gemm_dkv<<<g, 256, 0, stream>>>(ea_perm, &off[nlo], &off[nhi], WTdkv, Bdkv,
                                      dkdv, (int)CHmax);
    k_agg<<<nhi - nlo, 128, 0, stream>>>(dkdv, off, perm, snd, ew, evec, qk_b, v_b,
                                         vec_b, xagg, vecagg, nlo, nhi, (int)CHmax);
  }

  // o = x_agg @ Wo + bo   (qkv buffer is dead; reused as o / xagg_b)
  k_cast_bf16<<<cdiv_i((long long)NN * 64, 256), 256, 0, stream>>>(xagg, xagg_b, NN * 64);
  { dim3 g(384 / 128, cdiv_i(NN, 128));
    k_gemm<128, false, false><<<g, 256, 0, stream>>>(xagg_b, WTo, bo, o, NN, 384); }

  // outputs
  k_final<<<cdiv_i((long long)NN * 128, 256), 256, 0, stream>>>(o, vp, xagg, vecagg);
}

// Round 3
// 412.339 us; speedup vs baseline: 1.8863x; 1.2049x over previous
//
#include <hip/hip_runtime.h>
#include <stdint.h>

#define NN 20000
#define NE 200000
// H=128, NH=8, HD=16, RBF=64

typedef __attribute__((ext_vector_type(8))) short bf16x8;
typedef __attribute__((ext_vector_type(4))) float f32x4;

__device__ __forceinline__ float bf2f(uint32_t u) {
  union { uint32_t i; float f; } v; v.i = u << 16; return v.f;
}
__device__ __forceinline__ uint16_t f2bf(float f) {
  union { float f; uint32_t i; } v; v.f = f;
  return (uint16_t)((v.i + 0x7fffu + ((v.i >> 16) & 1u)) >> 16);
}
__device__ __forceinline__ float siluf(float x) { return x / (1.f + __expf(-x)); }

// ---------------- prep kernels ----------------

// dst[c*K + k] = bf16(src[k*C + c])   (dst is [C rows][K cols])
__global__ void k_transpose_cast(const float* __restrict__ src, uint16_t* __restrict__ dst,
                                 int K, int C) {
  int idx = blockIdx.x * 256 + threadIdx.x;
  if (idx >= K * C) return;
  int c = idx / K, k = idx - c * K;
  dst[idx] = f2bf(src[(size_t)k * C + c]);
}

__global__ void k_bias_concat(const float* __restrict__ bq, const float* __restrict__ bk,
                              const float* __restrict__ bv, const float* __restrict__ bdk,
                              const float* __restrict__ bdv, float* __restrict__ Bqkv,
                              float* __restrict__ Bdkv) {
  int t = blockIdx.x * 256 + threadIdx.x;
  if (t < 640) Bqkv[t] = (t < 128) ? bq[t] : ((t < 256) ? bk[t - 128] : bv[t - 256]);
  if (t < 512) Bdkv[t] = (t < 128) ? bdk[t] : bdv[t - 128];
}

// LayerNorm over H=128 per node, one wave per node, output bf16
__global__ void k_ln_cast(const float* __restrict__ x, const float* __restrict__ s,
                          const float* __restrict__ b, uint16_t* __restrict__ out) {
  int gt = blockIdx.x * 256 + threadIdx.x;
  int node = gt >> 6, lane = gt & 63;
  if (node >= NN) return;
  const float* row = x + (size_t)node * 128;
  float2 v = *(const float2*)&row[lane * 2];
  float sum = v.x + v.y, sq = v.x * v.x + v.y * v.y;
  #pragma unroll
  for (int off = 32; off; off >>= 1) { sum += __shfl_xor(sum, off); sq += __shfl_xor(sq, off); }
  float mu = sum * (1.f / 128.f);
  float var = sq * (1.f / 128.f) - mu * mu;
  float rs = rsqrtf(var + 1e-6f);
  float o0 = (v.x - mu) * rs * s[lane * 2] + b[lane * 2];
  float o1 = (v.y - mu) * rs * s[lane * 2 + 1] + b[lane * 2 + 1];
  ((uint32_t*)out)[(size_t)node * 64 + lane] = (uint32_t)f2bf(o0) | ((uint32_t)f2bf(o1) << 16);
}

__global__ void k_cast_bf16(const float* __restrict__ src, uint16_t* __restrict__ dst, int npairs) {
  int i = blockIdx.x * 256 + threadIdx.x;
  if (i >= npairs) return;
  float2 v = ((const float2*)src)[i];
  ((uint32_t*)dst)[i] = (uint32_t)f2bf(v.x) | ((uint32_t)f2bf(v.y) << 16);
}

// ---------------- edge sort by receiver (counting sort, parallel scan) ----------------
__global__ void k_hist(const int* __restrict__ rcv, int* __restrict__ deg) {
  int e = blockIdx.x * 256 + threadIdx.x;
  if (e < NE) atomicAdd(&deg[rcv[e]], 1);
}

// per-block sums of deg
__global__ void k_scan1(const int* __restrict__ deg, int* __restrict__ bsum) {
  __shared__ int ws[4];
  int i = blockIdx.x * 256 + threadIdx.x;
  int x = (i < NN) ? deg[i] : 0;
  #pragma unroll
  for (int d = 32; d; d >>= 1) x += __shfl_xor(x, d);
  if ((threadIdx.x & 63) == 0) ws[threadIdx.x >> 6] = x;
  __syncthreads();
  if (threadIdx.x == 0) bsum[blockIdx.x] = ws[0] + ws[1] + ws[2] + ws[3];
}

// single-wave exclusive scan of nb block sums (nb <= a few hundred)
__global__ void k_scan2(int* __restrict__ bsum, int nb, int* __restrict__ off) {
  int lane = threadIdx.x;
  int carry = 0;
  for (int base = 0; base < nb; base += 64) {
    int i = base + lane;
    int x = (i < nb) ? bsum[i] : 0;
    int v = x;
    #pragma unroll
    for (int d = 1; d < 64; d <<= 1) { int y = __shfl_up(v, d); if (lane >= d) v += y; }
    if (i < nb) bsum[i] = carry + v - x;
    carry += __shfl(v, 63);
  }
  if (lane == 0) off[NN] = carry;   // == NE
}

// local exclusive scan + block offset -> off, cur
__global__ void k_scan3(const int* __restrict__ deg, const int* __restrict__ bsum,
                        int* __restrict__ off, int* __restrict__ cur) {
  __shared__ int ws[4];
  int t = threadIdx.x, lane = t & 63, w = t >> 6;
  int i = blockIdx.x * 256 + t;
  int x = (i < NN) ? deg[i] : 0;
  int v = x;
  #pragma unroll
  for (int d = 1; d < 64; d <<= 1) { int y = __shfl_up(v, d); if (lane >= d) v += y; }
  if (lane == 63) ws[w] = v;
  __syncthreads();
  int wadd = 0;
  for (int j = 0; j < w; j++) wadd += ws[j];
  int excl = bsum[blockIdx.x] + wadd + v - x;
  if (i < NN) { off[i] = excl; cur[i] = excl; }
}

__global__ void k_scatter(const int* __restrict__ rcv, int* __restrict__ cur,
                          int* __restrict__ perm) {
  int e = blockIdx.x * 256 + threadIdx.x;
  if (e >= NE) return;
  int pos = atomicAdd(&cur[rcv[e]], 1);
  perm[pos] = e;
}

// gather+cast edge_attr rows in permuted order; also permute snd / ew / evec
__global__ void k_permute(const float* __restrict__ ea, const int* __restrict__ perm,
                          const int* __restrict__ snd, const float* __restrict__ ew,
                          const float* __restrict__ evec, uint16_t* __restrict__ ea_perm,
                          int* __restrict__ sndp, float4* __restrict__ edata) {
  int idx = blockIdx.x * 256 + threadIdx.x;   // 16 threads per edge
  if (idx >= NE * 16) return;
  int i = idx >> 4, j = idx & 15;
  int e = perm[i];
  float4 v = *(const float4*)&ea[(size_t)e * 64 + j * 4];
  uint2 o;
  o.x = (uint32_t)f2bf(v.x) | ((uint32_t)f2bf(v.y) << 16);
  o.y = (uint32_t)f2bf(v.z) | ((uint32_t)f2bf(v.w) << 16);
  *(uint2*)&ea_perm[(size_t)i * 64 + j * 4] = o;
  if (j == 0) {
    sndp[i] = snd[e];
    edata[i] = make_float4(evec[e * 3], evec[e * 3 + 1], evec[e * 3 + 2], ew[e]);
  }
}

// ---------------- bf16 MFMA GEMM: C = act(A @ BT^T + bias) ----------------
template <int KTOT, bool OUT_BF16, bool SILU>
__global__ __launch_bounds__(256) void k_gemm(const uint16_t* __restrict__ A,
                                              const uint16_t* __restrict__ BT,
                                              const float* __restrict__ bias,
                                              void* __restrict__ Cout, int M, int Fo) {
  __shared__ __align__(16) uint16_t As[128 * 72];
  __shared__ __align__(16) uint16_t Bs[128 * 72];
  int t = threadIdx.x;
  int l = t & 63;
  int row0 = blockIdx.y * 128, col0 = blockIdx.x * 128;
  int wm = ((t >> 6) >> 1) * 64, wn = ((t >> 6) & 1) * 64;
  f32x4 acc[4][4] = {};
  for (int kt = 0; kt < KTOT; kt += 64) {
    __syncthreads();
    #pragma unroll
    for (int i = 0; i < 4; i++) {
      int c = i * 256 + t;
      int row = c >> 3, ko = (c & 7) * 8;
      uint4 av = make_uint4(0u, 0u, 0u, 0u);
      int gr = row0 + row;
      if (gr < M) av = *(const uint4*)&A[(size_t)gr * KTOT + kt + ko];
      *(uint4*)&As[row * 72 + ko] = av;
      uint4 bw = *(const uint4*)&BT[(size_t)(col0 + row) * KTOT + kt + ko];
      *(uint4*)&Bs[row * 72 + ko] = bw;
    }
    __syncthreads();
    #pragma unroll
    for (int kk = 0; kk < 64; kk += 32) {
      bf16x8 af[4], bfr[4];
      #pragma unroll
      for (int mf = 0; mf < 4; mf++)
        af[mf] = *(const bf16x8*)&As[(wm + mf * 16 + (l & 15)) * 72 + (l >> 4) * 8 + kk];
      #pragma unroll
      for (int nf = 0; nf < 4; nf++)
        bfr[nf] = *(const bf16x8*)&Bs[(wn + nf * 16 + (l & 15)) * 72 + (l >> 4) * 8 + kk];
      #pragma unroll
      for (int mf = 0; mf < 4; mf++)
        #pragma unroll
        for (int nf = 0; nf < 4; nf++)
          acc[mf][nf] = __builtin_amdgcn_mfma_f32_16x16x32_bf16(af[mf], bfr[nf], acc[mf][nf], 0, 0, 0);
    }
  }
  float* Cf = (float*)Cout;
  uint16_t* Cb = (uint16_t*)Cout;
  #pragma unroll
  for (int mf = 0; mf < 4; mf++) {
    #pragma unroll
    for (int r = 0; r < 4; r++) {
      int grow = row0 + wm + mf * 16 + (l >> 4) * 4 + r;
      if (grow >= M) continue;
      #pragma unroll
      for (int nf = 0; nf < 4; nf++) {
        int gcol = col0 + wn + nf * 16 + (l & 15);
        float v = acc[mf][nf][r];
        if (bias) v += bias[gcol];
        if (SILU) v = siluf(v);
        if (OUT_BF16) Cb[(size_t)grow * Fo + gcol] = f2bf(v);
        else          Cf[(size_t)grow * Fo + gcol] = v;
      }
    }
  }
}

// dkdv GEMM over a node-chunk's edge range [off[n0], off[n1]) read from device.
__global__ __launch_bounds__(256) void k_gemm_dkv(const uint16_t* __restrict__ Aperm,
                                                  const int* __restrict__ pbeg,
                                                  const int* __restrict__ pend,
                                                  const uint16_t* __restrict__ BT,
                                                  const float* __restrict__ bias,
                                                  uint16_t* __restrict__ Cout, int Mcap) {
  int e0 = pbeg[0];
  int M = pend[0] - e0;
  if (M > Mcap) M = Mcap;
  int row0 = blockIdx.y * 128, col0 = blockIdx.x * 128;
  if (row0 >= M) return;
  const uint16_t* A = Aperm + (size_t)e0 * 64;
  __shared__ __align__(16) uint16_t As[128 * 72];
  __shared__ __align__(16) uint16_t Bs[128 * 72];
  int t = threadIdx.x;
  int l = t & 63;
  int wm = ((t >> 6) >> 1) * 64, wn = ((t >> 6) & 1) * 64;
  f32x4 acc[4][4] = {};
  {
    #pragma unroll
    for (int i = 0; i < 4; i++) {
      int c = i * 256 + t;
      int row = c >> 3, ko = (c & 7) * 8;
      uint4 av = make_uint4(0u, 0u, 0u, 0u);
      if (row0 + row < M) av = *(const uint4*)&A[(size_t)(row0 + row) * 64 + ko];
      *(uint4*)&As[row * 72 + ko] = av;
      uint4 bw = *(const uint4*)&BT[(size_t)(col0 + row) * 64 + ko];
      *(uint4*)&Bs[row * 72 + ko] = bw;
    }
    __syncthreads();
    #pragma unroll
    for (int kk = 0; kk < 64; kk += 32) {
      bf16x8 af[4], bfr[4];
      #pragma unroll
      for (int mf = 0; mf < 4; mf++)
        af[mf] = *(const bf16x8*)&As[(wm + mf * 16 + (l & 15)) * 72 + (l >> 4) * 8 + kk];
      #pragma unroll
      for (int nf = 0; nf < 4; nf++)
        bfr[nf] = *(const bf16x8*)&Bs[(wn + nf * 16 + (l & 15)) * 72 + (l >> 4) * 8 + kk];
      #pragma unroll
      for (int mf = 0; mf < 4; mf++)
        #pragma unroll
        for (int nf = 0; nf < 4; nf++)
          acc[mf][nf] = __builtin_amdgcn_mfma_f32_16x16x32_bf16(af[mf], bfr[nf], acc[mf][nf], 0, 0, 0);
    }
  }
  #pragma unroll
  for (int mf = 0; mf < 4; mf++) {
    #pragma unroll
    for (int r = 0; r < 4; r++) {
      int grow = row0 + wm + mf * 16 + (l >> 4) * 4 + r;
      if (grow >= M) continue;
      #pragma unroll
      for (int nf = 0; nf < 4; nf++) {
        int gcol = col0 + wn + nf * 16 + (l & 15);
        float v = siluf(acc[mf][nf][r] + bias[gcol]);
        Cout[(size_t)grow * 512 + gcol] = f2bf(v);
      }
    }
  }
}

// ---------------- per-head LN on q/k (bf16 in/out) ----------------
__global__ void k_headln(const uint16_t* __restrict__ qkv, const float* __restrict__ qs,
                         const float* __restrict__ qb, const float* __restrict__ ks,
                         const float* __restrict__ kb, uint16_t* __restrict__ out) {
  int idx = blockIdx.x * 256 + threadIdx.x;
  if (idx >= NN * 16) return;
  int n = idx >> 4, ph = idx & 15, part = ph >> 3, h = ph & 7;
  const uint16_t* src = qkv + (size_t)n * 640 + part * 128 + h * 16;
  float v[16], sum = 0.f;
  #pragma unroll
  for (int i = 0; i < 16; i++) { v[i] = bf2f(src[i]); sum += v[i]; }
  float mu = sum * (1.f / 16.f), var = 0.f;
  #pragma unroll
  for (int i = 0; i < 16; i++) { float d = v[i] - mu; var += d * d; }
  float rs = rsqrtf(var * (1.f / 16.f) + 1e-6f);
  const float* sc = part ? ks : qs;
  const float* bb = part ? kb : qb;
  uint16_t* dst = out + (size_t)n * 256 + part * 128 + h * 16;
  #pragma unroll
  for (int i = 0; i < 16; i++) dst[i] = f2bf((v[i] - mu) * rs * sc[i] + bb[i]);
}

// ---------------- fused attn + message + segment aggregation (no atomics) ----------------
__global__ __launch_bounds__(128) void k_agg(
    const uint16_t* __restrict__ dkdv, const int* __restrict__ off,
    const int* __restrict__ sndp, const float4* __restrict__ edata,
    const uint16_t* __restrict__ qk_b, const uint16_t* __restrict__ qkv_b,
    const uint16_t* __restrict__ vec_b, float* __restrict__ xagg,
    float* __restrict__ vecagg, int n0, int n1, int Mcap) {
  int n = n0 + blockIdx.x;
  if (n >= n1) return;
  int hd = threadIdx.x, h = hd >> 4, d = hd & 15;
  int i0 = off[n], i1 = off[n + 1];
  int ebase = off[n0];
  float q = bf2f(qk_b[(size_t)n * 256 + hd]);
  int vb = h * 48 + d;
  float ax = 0.f, a0 = 0.f, a1 = 0.f, a2 = 0.f;
  for (int i = i0; i < i1; i++) {
    int li = i - ebase;
    if (li >= Mcap) break;
    int s = sndp[i];
    float4 ed = edata[i];
    const uint16_t* row = dkdv + (size_t)li * 512;
    float dk = bf2f(row[hd]);
    float kv = bf2f(qk_b[(size_t)s * 256 + 128 + hd]);
    float t = q * kv * dk;
    t += __shfl_xor(t, 1); t += __shfl_xor(t, 2);
    t += __shfl_xor(t, 4); t += __shfl_xor(t, 8);
    float w = ed.w;
    float cut = (w < 5.f) ? 0.5f * (__cosf(w * 0.628318530717958648f) + 1.f) : 0.f;
    float a = (t / (1.f + __expf(-t))) * cut;
    float dv0 = bf2f(row[128 + vb]), dv1 = bf2f(row[144 + vb]), dv2 = bf2f(row[160 + vb]);
    const uint16_t* vsp = qkv_b + (size_t)s * 640 + 256 + vb;
    float m1 = bf2f(vsp[16]) * dv1;
    float m2 = bf2f(vsp[32]) * dv2;
    ax += bf2f(vsp[0]) * dv0 * a;
    const uint16_t* vv = vec_b + (size_t)s * 384;
    a0 += bf2f(vv[hd]) * m1 + m2 * ed.x;
    a1 += bf2f(vv[128 + hd]) * m1 + m2 * ed.y;
    a2 += bf2f(vv[256 + hd]) * m1 + m2 * ed.z;
  }
  xagg[(size_t)n * 128 + hd] = ax;
  vecagg[((size_t)n * 3 + 0) * 128 + hd] = a0;
  vecagg[((size_t)n * 3 + 1) * 128 + hd] = a1;
  vecagg[((size_t)n * 3 + 2) * 128 + hd] = a2;
}

// ---------------- final: dx = vec_dot*o2+o3 ; dvec = vec3*o1 + vec_agg ----------------
__global__ void k_final(const float* __restrict__ o, const uint16_t* __restrict__ vp,
                        float* __restrict__ dx, float* __restrict__ dvec) {
  int idx = blockIdx.x * 256 + threadIdx.x;
  if (idx >= NN * 128) return;
  int n = idx >> 7, j = idx & 127;
  const float* op = o + (size_t)n * 384;
  float o1 = op[j], o2 = op[128 + j], o3 = op[256 + j];
  const uint16_t* vpn = vp + (size_t)n * 3 * 384;
  float vd = 0.f;
  #pragma unroll
  for (int c = 0; c < 3; c++)
    vd += bf2f(vpn[c * 384 + j]) * bf2f(vpn[c * 384 + 128 + j]);
  dx[idx] = vd * o2 + o3;
  #pragma unroll
  for (int c = 0; c < 3; c++) {
    size_t vi = ((size_t)n * 3 + c) * 128 + j;
    dvec[vi] = bf2f(vpn[c * 384 + 256 + j]) * o1 + dvec[vi];
  }
}

static inline int cdiv_i(long long a, long long b) { return (int)((a + b - 1) / b); }

extern "C" void kernel_launch(void* const* d_in, const int* in_sizes, int n_in,
                              void* d_out, int out_size, void* d_ws, size_t ws_size,
                              hipStream_t stream) {
  const float* x    = (const float*)d_in[0];
  const float* vec  = (const float*)d_in[1];
  const float* ew   = (const float*)d_in[2];
  const float* ea   = (const float*)d_in[3];
  const float* evec = (const float*)d_in[4];
  const int*   snd  = (const int*)d_in[5];
  const int*   rcv  = (const int*)d_in[6];
  const float* ln_s = (const float*)d_in[7];
  const float* ln_b = (const float*)d_in[8];
  const float* Wq = (const float*)d_in[9];   const float* bq = (const float*)d_in[10];
  const float* Wk = (const float*)d_in[11];  const float* bk = (const float*)d_in[12];
  const float* Wv = (const float*)d_in[13];  const float* bv = (const float*)d_in[14];
  const float* Wvec = (const float*)d_in[15];
  const float* Wdk = (const float*)d_in[16]; const float* bdk = (const float*)d_in[17];
  const float* Wdv = (const float*)d_in[18]; const float* bdv = (const float*)d_in[19];
  const float* Wo = (const float*)d_in[20];  const float* bo = (const float*)d_in[21];
  const float* qln_s = (const float*)d_in[22]; const float* qln_b = (const float*)d_in[23];
  const float* kln_s = (const float*)d_in[24]; const float* kln_b = (const float*)d_in[25];
  (void)in_sizes; (void)n_in; (void)out_size;

  uint8_t* p = (uint8_t*)d_ws;
  auto alloc = [&](size_t bytes) -> uint8_t* {
    uint8_t* r = p; p += (bytes + 255) & ~(size_t)255; return r;
  };
  uint16_t* WTqkv = (uint16_t*)alloc(640 * 128 * 2);
  float*    Bqkv  = (float*)alloc(640 * 4);
  uint16_t* WTvec = (uint16_t*)alloc(384 * 128 * 2);
  uint16_t* WTdkv = (uint16_t*)alloc(512 * 64 * 2);
  float*    Bdkv  = (float*)alloc(512 * 4);
  uint16_t* WTo   = (uint16_t*)alloc(384 * 128 * 2);
  int*      deg   = (int*)alloc(NN * 4);
  int*      off   = (int*)alloc((NN + 1) * 4);
  int*      cur   = (int*)alloc(NN * 4);
  int*      bsum  = (int*)alloc(256 * 4);
  int*      perm  = (int*)alloc((size_t)NE * 4);
  int*      sndp  = (int*)alloc((size_t)NE * 4);
  float4*   edata = (float4*)alloc((size_t)NE * 16);
  uint16_t* xn_b  = (uint16_t*)alloc((size_t)NN * 128 * 2);
  uint16_t* qkv_b = (uint16_t*)alloc((size_t)NN * 640 * 2);
  uint16_t* qk_b  = (uint16_t*)alloc((size_t)NN * 256 * 2);
  uint16_t* vec_b = (uint16_t*)alloc((size_t)NN * 3 * 128 * 2);
  uint16_t* vp    = (uint16_t*)alloc((size_t)NN * 3 * 384 * 2);
  uint16_t* ea_perm = (uint16_t*)alloc((size_t)NE * 64 * 2);
  float*    o      = (float*)alloc((size_t)NN * 384 * 4);
  uint16_t* xagg_b = (uint16_t*)alloc((size_t)NN * 128 * 2);
  size_t fixed = (size_t)(p - (uint8_t*)d_ws);

  // adaptive node-chunking for the dkdv buffer
  int nchunk = 1;
  long long CHmax = NE;
  for (nchunk = 1; nchunk <= 64; nchunk++) {
    long long base = (NE + nchunk - 1) / nchunk;
    CHmax = (nchunk == 1) ? (long long)NE : base + base / 4;   // 1.25x margin
    if (fixed + (size_t)CHmax * 1024 + 4096 <= ws_size) break;
  }
  uint16_t* dkdv = (uint16_t*)alloc((size_t)CHmax * 1024);
  int NB = cdiv_i(NN, nchunk);

  float* xagg   = (float*)d_out;
  float* vecagg = (float*)d_out + (size_t)NN * 128;

  // ---- weights prep ----
  k_transpose_cast<<<cdiv_i(128 * 128, 256), 256, 0, stream>>>(Wq, WTqkv, 128, 128);
  k_transpose_cast<<<cdiv_i(128 * 128, 256), 256, 0, stream>>>(Wk, WTqkv + 128 * 128, 128, 128);
  k_transpose_cast<<<cdiv_i(384 * 128, 256), 256, 0, stream>>>(Wv, WTqkv + 256 * 128, 128, 384);
  k_transpose_cast<<<cdiv_i(384 * 128, 256), 256, 0, stream>>>(Wvec, WTvec, 128, 384);
  k_transpose_cast<<<cdiv_i(128 * 64, 256), 256, 0, stream>>>(Wdk, WTdkv, 64, 128);
  k_transpose_cast<<<cdiv_i(384 * 64, 256), 256, 0, stream>>>(Wdv, WTdkv + 128 * 64, 64, 384);
  k_transpose_cast<<<cdiv_i(384 * 128, 256), 256, 0, stream>>>(Wo, WTo, 128, 384);
  k_bias_concat<<<3, 256, 0, stream>>>(bq, bk, bv, bdk, bdv, Bqkv, Bdkv);

  // ---- edge sort by receiver ----
  int NSB = cdiv_i(NN, 256);   // 79
  hipMemsetAsync(deg, 0, NN * 4, stream);
  k_hist<<<cdiv_i(NE, 256), 256, 0, stream>>>(rcv, deg);
  k_scan1<<<NSB, 256, 0, stream>>>(deg, bsum);
  k_scan2<<<1, 64, 0, stream>>>(bsum, NSB, off);
  k_scan3<<<NSB, 256, 0, stream>>>(deg, bsum, off, cur);
  k_scatter<<<cdiv_i(NE, 256), 256, 0, stream>>>(rcv, cur, perm);
  k_permute<<<cdiv_i((long long)NE * 16, 256), 256, 0, stream>>>(ea, perm, snd, ew, evec,
                                                                 ea_perm, sndp, edata);

  // ---- node pre ----
  k_ln_cast<<<cdiv_i((long long)NN * 64, 256), 256, 0, stream>>>(x, ln_s, ln_b, xn_b);
  k_cast_bf16<<<cdiv_i((long long)NN * 3 * 64, 256), 256, 0, stream>>>(vec, vec_b, NN * 3 * 64);

  // qkv = xn @ [Wq|Wk|Wv] + b  (bf16 out)
  { dim3 g(640 / 128, cdiv_i(NN, 128));
    k_gemm<128, true, false><<<g, 256, 0, stream>>>(xn_b, WTqkv, Bqkv, qkv_b, NN, 640); }
  k_headln<<<cdiv_i((long long)NN * 16, 256), 256, 0, stream>>>(qkv_b, qln_s, qln_b, kln_s, kln_b, qk_b);

  // vp = vec @ Wvec (bf16 out)
  { dim3 g(384 / 128, cdiv_i((long long)NN * 3, 128));
    k_gemm<128, true, false><<<g, 256, 0, stream>>>(vec_b, WTvec, nullptr, vp, NN * 3, 384); }

  // ---- edge phase: per node-chunk, dkdv GEMM then segment aggregation ----
  for (int c = 0; c < nchunk; c++) {
    int nlo = c * NB, nhi = (c + 1) * NB; if (nhi > NN) nhi = NN;
    if (nlo >= nhi) break;
    dim3 g(512 / 128, cdiv_i(CHmax, 128));
    k_gemm_dkv<<<g, 256, 0, stream>>>(ea_perm, &off[nlo], &off[nhi], WTdkv, Bdkv,
                                      dkdv, (int)CHmax);
    k_agg<<<nhi - nlo, 128, 0, stream>>>(dkdv, off, sndp, edata, qk_b, qkv_b,
                                         vec_b, xagg, vecagg, nlo, nhi, (int)CHmax);
  }

  // o = x_agg @ Wo + bo
  k_cast_bf16<<<cdiv_i((long long)NN * 64, 256), 256, 0, stream>>>(xagg, xagg_b, NN * 64);
  { dim3 g(384 / 128, cdiv_i(NN, 128));
    k_gemm<128, false, false><<<g, 256, 0, stream>>>(xagg_b, WTo, bo, o, NN, 384); }

  // outputs
  k_final<<<cdiv_i((long long)NN * 128, 256), 256, 0, stream>>>(o, vp, xagg, vecagg);
}